// Round 1
// baseline (1254.465 us; speedup 1.0000x reference)
//
#include <hip/hip_runtime.h>
#include <math.h>

// Problem constants: B=2, spatial 64^3, C=64, modes 16 -> F=32 kept freqs/axis,
// heads=8, key=val=16, patch 4^3 -> tokens L=512, grouped channels R=1024.

static __device__ __forceinline__ float selu_f(float v) {
    return 1.0507009873554805f * (v > 0.f ? v : 1.6732632423543772f * (expf(v) - 1.f));
}

// Fill LDS tables ct/st[32][64]: row r -> freq k = r<16 ? r : r+32; ct = cos(2pi k n/64).
static __device__ __forceinline__ void fill_tables(float* ct, float* st, int t, int nthr) {
    for (int i = t; i < 2048; i += nthr) {
        int r = i >> 6, n = i & 63;
        int k = (r < 16) ? r : (r + 32);
        float ang = (float)((k * n) & 63) * 0.09817477042468103f; // 2*pi/64
        float s, c;
        sincosf(ang, &s, &c);
        ct[i] = c; st[i] = s;
    }
}

// ---------------- forward stage 1: partial DFT along W (real in, 32 corner freqs out)
// x: (B,D,H,W,C) -> re1/im1: (B,D,H,F2=32,C)
__global__ __launch_bounds__(256) void k_fwd_w(const float* __restrict__ x,
                                               float* __restrict__ re1, float* __restrict__ im1) {
    __shared__ float xs[4096];            // [w][c]
    __shared__ float ct[2048], st[2048];
    const int blk = blockIdx.x;           // (b*64+d)*64+h
    const int t = threadIdx.x;
    const float* xp = x + (size_t)blk * 4096;
    for (int i = t; i < 4096; i += 256) xs[i] = xp[i];
    fill_tables(ct, st, t, 256);
    __syncthreads();
    #pragma unroll 1
    for (int rep = 0; rep < 8; ++rep) {
        const int o = t + rep * 256;
        const int f = o >> 6, c = o & 63;
        float ar = 0.f, ai = 0.f;
        #pragma unroll
        for (int w = 0; w < 64; ++w) {
            const float xv = xs[w * 64 + c];
            ar = fmaf(xv, ct[f * 64 + w], ar);
            ai = fmaf(xv, -st[f * 64 + w], ai);
        }
        const size_t dst = (size_t)blk * 2048 + o;
        re1[dst] = ar; im1[dst] = ai;
    }
}

// ---------------- forward stage 2: partial DFT along H (complex in/out)
// (B,D,H,F2,C) -> (B,D,F1,F2,C)
__global__ __launch_bounds__(256) void k_fwd_h(const float* __restrict__ re1, const float* __restrict__ im1,
                                               float* __restrict__ re2, float* __restrict__ im2) {
    __shared__ float rs[4096], is[4096];  // [h][c]
    __shared__ float ct[2048], st[2048];
    const int blk = blockIdx.x;           // bd*32 + f2, bd = b*64+d
    const int f2 = blk & 31, bd = blk >> 5;
    const int t = threadIdx.x;
    for (int i = t; i < 4096; i += 256) {
        const int h = i >> 6, c = i & 63;
        const size_t src = ((size_t)(bd * 64 + h) * 32 + f2) * 64 + c;
        rs[i] = re1[src]; is[i] = im1[src];
    }
    fill_tables(ct, st, t, 256);
    __syncthreads();
    #pragma unroll 1
    for (int rep = 0; rep < 8; ++rep) {
        const int o = t + rep * 256;
        const int f1 = o >> 6, c = o & 63;
        float ar = 0.f, ai = 0.f;
        #pragma unroll
        for (int h = 0; h < 64; ++h) {
            const float cv = ct[f1 * 64 + h], sv = st[f1 * 64 + h];
            const float rv = rs[h * 64 + c], iv = is[h * 64 + c];
            ar += rv * cv + iv * sv;
            ai += iv * cv - rv * sv;
        }
        const size_t dst = ((size_t)(bd * 32 + f1) * 32 + f2) * 64 + c;
        re2[dst] = ar; im2[dst] = ai;
    }
}

// ---------------- forward stage 3: partial DFT along D + Hartley combine (Re - Im)
// (B,D,F1,F2,C) -> xt: (B,F0,F1,F2,C)
__global__ __launch_bounds__(256) void k_fwd_d(const float* __restrict__ re2, const float* __restrict__ im2,
                                               float* __restrict__ xt) {
    __shared__ float rs[4096], is[4096];  // [d][c]
    __shared__ float ct[2048], st[2048];
    const int blk = blockIdx.x;           // b*1024 + f1*32 + f2
    const int f2 = blk & 31, f1 = (blk >> 5) & 31, b = blk >> 10;
    const int t = threadIdx.x;
    for (int i = t; i < 4096; i += 256) {
        const int d = i >> 6, c = i & 63;
        const size_t src = (((size_t)(b * 64 + d) * 32 + f1) * 32 + f2) * 64 + c;
        rs[i] = re2[src]; is[i] = im2[src];
    }
    fill_tables(ct, st, t, 256);
    __syncthreads();
    #pragma unroll 1
    for (int rep = 0; rep < 8; ++rep) {
        const int o = t + rep * 256;
        const int f0 = o >> 6, c = o & 63;
        float acc = 0.f;
        #pragma unroll
        for (int d = 0; d < 64; ++d) {
            const float cv = ct[f0 * 64 + d], sv = st[f0 * 64 + d];
            acc += rs[d * 64 + c] * (cv + sv) + is[d * 64 + c] * (sv - cv);
        }
        const size_t dst = (((size_t)(b * 32 + f0) * 32 + f1) * 32 + f2) * 64 + c;
        xt[dst] = acc;
    }
}

// ---------------- QKV projection + frequency-patch grouping
// xt (B,32,32,32,C) -> Q/K/V: (B, NH=8, L=512, R=1024), R = key*64 + pd*16+ph*4+pw
__global__ __launch_bounds__(128) void k_qkv(const float* __restrict__ xt,
                                             const float* __restrict__ Wq, const float* __restrict__ Wk,
                                             const float* __restrict__ Wv,
                                             float* __restrict__ Qb, float* __restrict__ Kb,
                                             float* __restrict__ Vb) {
    __shared__ float xs[64][65];          // [pofs][c], +1 pad
    const int blk = blockIdx.x;           // b*512 + l
    const int l = blk & 511, b = blk >> 9;
    const int nw = l & 7, nh = (l >> 3) & 7, nd = l >> 6;
    const int t = threadIdx.x;            // 128
    for (int i = t; i < 4096; i += 128) {
        const int pofs = i >> 6, c = i & 63;
        const int f0 = nd * 4 + (pofs >> 4);
        const int f1 = nh * 4 + ((pofs >> 2) & 3);
        const int f2 = nw * 4 + (pofs & 3);
        xs[pofs][c] = xt[((((size_t)b * 32 + f0) * 32 + f1) * 32 + f2) * 64 + c];
    }
    __syncthreads();
    const int kn = t;                     // key = kn>>3, n = kn&7; W index c*128 + kn
    const int key = kn >> 3, n = kn & 7;
    #pragma unroll 1
    for (int p0 = 0; p0 < 64; p0 += 16) {
        float accq[16], acck[16], accv[16];
        #pragma unroll
        for (int i = 0; i < 16; ++i) { accq[i] = 0.f; acck[i] = 0.f; accv[i] = 0.f; }
        #pragma unroll 1
        for (int c0 = 0; c0 < 64; c0 += 16) {
            float wq[16], wk[16], wv[16];
            #pragma unroll
            for (int c = 0; c < 16; ++c) {
                wq[c] = Wq[(c0 + c) * 128 + kn];
                wk[c] = Wk[(c0 + c) * 128 + kn];
                wv[c] = Wv[(c0 + c) * 128 + kn];
            }
            #pragma unroll
            for (int p = 0; p < 16; ++p) {
                #pragma unroll
                for (int c = 0; c < 16; ++c) {
                    const float xv = xs[p0 + p][c0 + c];
                    accq[p] = fmaf(xv, wq[c], accq[p]);
                    acck[p] = fmaf(xv, wk[c], acck[p]);
                    accv[p] = fmaf(xv, wv[c], accv[p]);
                }
            }
        }
        const size_t base = (((size_t)(b * 8 + n) * 512 + l) * 1024 + key * 64 + p0);
        #pragma unroll
        for (int p = 0; p < 16; ++p) {
            Qb[base + p] = accq[p]; Kb[base + p] = acck[p]; Vb[base + p] = accv[p];
        }
    }
}

// ---------------- attention GEMM 1: A = selu(Q K^T), per (b,h): (512x1024)*(512x1024)^T
__global__ __launch_bounds__(256) void k_attn_qk(const float* __restrict__ Qm,
                                                 const float* __restrict__ Km,
                                                 float* __restrict__ Am) {
    __shared__ float As[16][128];
    __shared__ float Bs[16][64];
    const int bh = blockIdx.z;
    const float* Ap = Qm + (size_t)bh * 512 * 1024;
    const float* Bp = Km + (size_t)bh * 512 * 1024;
    float* Cp = Am + (size_t)bh * 512 * 512;
    const int m0 = blockIdx.y * 128, n0 = blockIdx.x * 64;
    const int t = threadIdx.x;
    const int tx = t & 15, ty = t >> 4;
    float acc[8][4] = {};
    for (int k0 = 0; k0 < 1024; k0 += 16) {
        #pragma unroll
        for (int u = 0; u < 2; ++u) {
            const int idx = t + u * 256;
            const int r = idx >> 2, cc = (idx & 3) * 4;
            const float4 v = *(const float4*)&Ap[(size_t)(m0 + r) * 1024 + k0 + cc];
            As[cc + 0][r] = v.x; As[cc + 1][r] = v.y; As[cc + 2][r] = v.z; As[cc + 3][r] = v.w;
        }
        {
            const int r = t >> 2, cc = (t & 3) * 4;
            const float4 v = *(const float4*)&Bp[(size_t)(n0 + r) * 1024 + k0 + cc];
            Bs[cc + 0][r] = v.x; Bs[cc + 1][r] = v.y; Bs[cc + 2][r] = v.z; Bs[cc + 3][r] = v.w;
        }
        __syncthreads();
        #pragma unroll
        for (int kk = 0; kk < 16; ++kk) {
            const float4 a0 = *(const float4*)&As[kk][ty * 8];
            const float4 a1 = *(const float4*)&As[kk][ty * 8 + 4];
            const float4 b0 = *(const float4*)&Bs[kk][tx * 4];
            const float av[8] = {a0.x, a0.y, a0.z, a0.w, a1.x, a1.y, a1.z, a1.w};
            const float bv[4] = {b0.x, b0.y, b0.z, b0.w};
            #pragma unroll
            for (int i = 0; i < 8; ++i)
                #pragma unroll
                for (int j = 0; j < 4; ++j)
                    acc[i][j] = fmaf(av[i], bv[j], acc[i][j]);
        }
        __syncthreads();
    }
    #pragma unroll
    for (int i = 0; i < 8; ++i) {
        float4 o;
        o.x = selu_f(acc[i][0]); o.y = selu_f(acc[i][1]);
        o.z = selu_f(acc[i][2]); o.w = selu_f(acc[i][3]);
        *(float4*)&Cp[(size_t)(m0 + ty * 8 + i) * 512 + n0 + tx * 4] = o;
    }
}

// ---------------- attention GEMM 2: O = A V, per (b,h): (512x512)*(512x1024)
__global__ __launch_bounds__(256) void k_attn_pv(const float* __restrict__ Am,
                                                 const float* __restrict__ Vm,
                                                 float* __restrict__ Om) {
    __shared__ float As[16][128];
    __shared__ float Bs[16][64];
    const int bh = blockIdx.z;
    const float* Ap = Am + (size_t)bh * 512 * 512;
    const float* Bp = Vm + (size_t)bh * 512 * 1024;
    float* Cp = Om + (size_t)bh * 512 * 1024;
    const int m0 = blockIdx.y * 128, n0 = blockIdx.x * 64;
    const int t = threadIdx.x;
    const int tx = t & 15, ty = t >> 4;
    float acc[8][4] = {};
    for (int k0 = 0; k0 < 512; k0 += 16) {
        #pragma unroll
        for (int u = 0; u < 2; ++u) {
            const int idx = t + u * 256;
            const int r = idx >> 2, cc = (idx & 3) * 4;
            const float4 v = *(const float4*)&Ap[(size_t)(m0 + r) * 512 + k0 + cc];
            As[cc + 0][r] = v.x; As[cc + 1][r] = v.y; As[cc + 2][r] = v.z; As[cc + 3][r] = v.w;
        }
        {
            const int kk = t >> 4, c4 = (t & 15) * 4;
            const float4 v = *(const float4*)&Bp[(size_t)(k0 + kk) * 1024 + n0 + c4];
            *(float4*)&Bs[kk][c4] = v;
        }
        __syncthreads();
        #pragma unroll
        for (int kk = 0; kk < 16; ++kk) {
            const float4 a0 = *(const float4*)&As[kk][ty * 8];
            const float4 a1 = *(const float4*)&As[kk][ty * 8 + 4];
            const float4 b0 = *(const float4*)&Bs[kk][tx * 4];
            const float av[8] = {a0.x, a0.y, a0.z, a0.w, a1.x, a1.y, a1.z, a1.w};
            const float bv[4] = {b0.x, b0.y, b0.z, b0.w};
            #pragma unroll
            for (int i = 0; i < 8; ++i)
                #pragma unroll
                for (int j = 0; j < 4; ++j)
                    acc[i][j] = fmaf(av[i], bv[j], acc[i][j]);
        }
        __syncthreads();
    }
    #pragma unroll
    for (int i = 0; i < 8; ++i) {
        float4 o; o.x = acc[i][0]; o.y = acc[i][1]; o.z = acc[i][2]; o.w = acc[i][3];
        *(float4*)&Cp[(size_t)(m0 + ty * 8 + i) * 1024 + n0 + tx * 4] = o;
    }
}

// ---------------- output projection + ungrouping: op[b,f0,f1,f2,o] = sum_{val,h} O * Wo
__global__ __launch_bounds__(256) void k_oproj(const float* __restrict__ Ob,
                                               const float* __restrict__ Wo,
                                               float* __restrict__ op) {
    __shared__ float Os[8][1024];
    __shared__ float Ws[2048];
    const int blk = blockIdx.x;           // b*512 + l
    const int l = blk & 511, b = blk >> 9;
    const int t = threadIdx.x;
    for (int i = t; i < 8192; i += 256) {
        const int h = i >> 10, r = i & 1023;
        Os[h][r] = Ob[((size_t)(b * 8 + h) * 512 + l) * 1024 + r];
    }
    for (int i = t; i < 2048; i += 256) Ws[i] = Wo[i];
    __syncthreads();
    const int pofs = t >> 2, o0 = (t & 3) * 4;
    float acc[4] = {0.f, 0.f, 0.f, 0.f};
    #pragma unroll
    for (int h = 0; h < 8; ++h) {
        #pragma unroll
        for (int val = 0; val < 16; ++val) {
            const float ov = Os[h][val * 64 + pofs];
            const int wi = (val * 8 + h) * 16;
            #pragma unroll
            for (int j = 0; j < 4; ++j) acc[j] = fmaf(ov, Ws[wi + o0 + j], acc[j]);
        }
    }
    const int nw = l & 7, nh = (l >> 3) & 7, nd = l >> 6;
    const int f0 = nd * 4 + (pofs >> 4);
    const int f1 = nh * 4 + ((pofs >> 2) & 3);
    const int f2 = nw * 4 + (pofs & 3);
    const size_t base = ((((size_t)b * 32 + f0) * 32 + f1) * 32 + f2) * 16 + o0;
    op[base + 0] = acc[0]; op[base + 1] = acc[1]; op[base + 2] = acc[2]; op[base + 3] = acc[3];
}

// ---------------- inverse stage 1: corner freqs (32) -> spatial D (64), real in, complex out
__global__ __launch_bounds__(256) void k_inv_d(const float* __restrict__ op,
                                               float* __restrict__ ire, float* __restrict__ iim) {
    __shared__ float s[512];              // [r0][o]
    __shared__ float ct[2048], st[2048];
    const int blk = blockIdx.x;           // b*1024 + k1*32 + k2
    const int k2 = blk & 31, k1 = (blk >> 5) & 31, b = blk >> 10;
    const int t = threadIdx.x;
    for (int i = t; i < 512; i += 256) {
        const int r0 = i >> 4, o = i & 15;
        s[i] = op[((((size_t)b * 32 + r0) * 32 + k1) * 32 + k2) * 16 + o];
    }
    fill_tables(ct, st, t, 256);
    __syncthreads();
    #pragma unroll 1
    for (int rep = 0; rep < 4; ++rep) {
        const int idx = t + rep * 256;
        const int d = idx >> 4, o = idx & 15;
        float ar = 0.f, ai = 0.f;
        #pragma unroll
        for (int r0 = 0; r0 < 32; ++r0) {
            const float v = s[r0 * 16 + o];
            ar = fmaf(v, ct[r0 * 64 + d], ar);
            ai = fmaf(v, -st[r0 * 64 + d], ai);
        }
        const size_t dst = ((((size_t)b * 64 + d) * 32 + k1) * 32 + k2) * 16 + o;
        ire[dst] = ar; iim[dst] = ai;
    }
}

// ---------------- inverse stage 2: along k1 -> H
__global__ __launch_bounds__(256) void k_inv_h(const float* __restrict__ ire, const float* __restrict__ iim,
                                               float* __restrict__ ore, float* __restrict__ oim) {
    __shared__ float sr[512], si[512];
    __shared__ float ct[2048], st[2048];
    const int blk = blockIdx.x;           // b*2048 + d*32 + k2
    const int k2 = blk & 31, d = (blk >> 5) & 63, b = blk >> 11;
    const int t = threadIdx.x;
    for (int i = t; i < 512; i += 256) {
        const int r1 = i >> 4, o = i & 15;
        const size_t src = ((((size_t)b * 64 + d) * 32 + r1) * 32 + k2) * 16 + o;
        sr[i] = ire[src]; si[i] = iim[src];
    }
    fill_tables(ct, st, t, 256);
    __syncthreads();
    #pragma unroll 1
    for (int rep = 0; rep < 4; ++rep) {
        const int idx = t + rep * 256;
        const int h = idx >> 4, o = idx & 15;
        float ar = 0.f, ai = 0.f;
        #pragma unroll
        for (int r1 = 0; r1 < 32; ++r1) {
            const float cv = ct[r1 * 64 + h], sv = st[r1 * 64 + h];
            const float rv = sr[r1 * 16 + o], iv = si[r1 * 16 + o];
            ar += rv * cv + iv * sv;
            ai += iv * cv - rv * sv;
        }
        const size_t dst = ((((size_t)b * 64 + d) * 64 + h) * 32 + k2) * 16 + o;
        ore[dst] = ar; oim[dst] = ai;
    }
}

// ---------------- inverse stage 3: along k2 -> W, Hartley combine, /N^3, write output
__global__ __launch_bounds__(256) void k_inv_w(const float* __restrict__ ire, const float* __restrict__ iim,
                                               float* __restrict__ outp) {
    __shared__ float sr[512], si[512];
    __shared__ float ct[2048], st[2048];
    const int blk = blockIdx.x;           // b*4096 + d*64 + h
    const int t = threadIdx.x;
    for (int i = t; i < 512; i += 256) {
        const size_t src = (size_t)blk * 512 + i;
        sr[i] = ire[src]; si[i] = iim[src];
    }
    fill_tables(ct, st, t, 256);
    __syncthreads();
    #pragma unroll 1
    for (int rep = 0; rep < 4; ++rep) {
        const int idx = t + rep * 256;
        const int w = idx >> 4, o = idx & 15;
        float acc = 0.f;
        #pragma unroll
        for (int r2 = 0; r2 < 32; ++r2) {
            const float cv = ct[r2 * 64 + w], sv = st[r2 * 64 + w];
            acc += sr[r2 * 16 + o] * (cv + sv) + si[r2 * 16 + o] * (sv - cv);
        }
        outp[((size_t)blk * 64 + w) * 16 + o] = acc * 3.814697265625e-06f; // 1/64^3
    }
}

extern "C" void kernel_launch(void* const* d_in, const int* in_sizes, int n_in,
                              void* d_out, int out_size, void* d_ws, size_t ws_size,
                              hipStream_t stream) {
    const float* x  = (const float*)d_in[0];
    const float* Wq = (const float*)d_in[1];
    const float* Wk = (const float*)d_in[2];
    const float* Wv = (const float*)d_in[3];
    const float* Wo = (const float*)d_in[4];
    float* outp = (float*)d_out;
    float* ws = (float*)d_ws;

    // Workspace arenas (floats). Peak ~235 MB, with buffer reuse across phases.
    float* re1  = ws;                   // [0, 16777216)         fwd stage1 Re
    float* im1  = ws + 16777216;        // [16777216, 33554432)  fwd stage1 Im
    float* re2  = ws + 33554432;        // [33554432, 41943040)  fwd stage2 Re
    float* im2  = ws + 41943040;        // [41943040, 50331648)  fwd stage2 Im
    float* xt   = ws;                   // 4194304  (reuses re1; re1 dead after stage2)
    float* Qb   = ws + 4194304;         // 8388608
    float* attn = ws + 12582912;        // 4194304
    float* Kb   = ws + 33554432;        // 8388608  (reuses re2; dead after stage3)
    float* Vb   = ws + 41943040;        // 8388608  (reuses im2)
    float* Ob   = ws + 50331648;        // 8388608
    float* op   = ws + 16777216;        // 1048576  (reuses im1)
    float* ire1 = ws + 17825792;        // 2097152
    float* iim1 = ws + 19922944;        // 2097152
    float* ire2 = ws + 22020096;        // 4194304
    float* iim2 = ws + 26214400;        // 4194304  (ends 30408704 < 33554432)

    k_fwd_w<<<8192, 256, 0, stream>>>(x, re1, im1);
    k_fwd_h<<<4096, 256, 0, stream>>>(re1, im1, re2, im2);
    k_fwd_d<<<2048, 256, 0, stream>>>(re2, im2, xt);
    k_qkv<<<1024, 128, 0, stream>>>(xt, Wq, Wk, Wv, Qb, Kb, Vb);
    k_attn_qk<<<dim3(8, 4, 16), 256, 0, stream>>>(Qb, Kb, attn);
    k_attn_pv<<<dim3(16, 4, 16), 256, 0, stream>>>(attn, Vb, Ob);
    k_oproj<<<1024, 256, 0, stream>>>(Ob, Wo, op);
    k_inv_d<<<2048, 256, 0, stream>>>(op, ire1, iim1);
    k_inv_h<<<4096, 256, 0, stream>>>(ire1, iim1, ire2, iim2);
    k_inv_w<<<8192, 256, 0, stream>>>(ire2, iim2, outp);
}

// Round 2
// 535.223 us; speedup vs baseline: 2.3438x; 2.3438x over previous
//
#include <hip/hip_runtime.h>
#include <math.h>

// B=2, spatial 64^3, C=64, F=32 kept freqs/axis, heads=8, key=val=16,
// patch 4^3 -> tokens L=512, grouped channels R=1024.

typedef _Float16 half8 __attribute__((ext_vector_type(8)));
typedef float f32x4 __attribute__((ext_vector_type(4)));

static __device__ __forceinline__ float selu_f(float v) {
    return 1.0507009873554805f * (v > 0.f ? v : 1.6732632423543772f * (expf(v) - 1.f));
}

// ---------------- twiddle tables (written once per launch to ws)
// tab[0..2048)   twF  [n][f]  (c, s)        forward stages 1,2
// tab[2048..4096) twFd [n][f] (c+s, s-c)    forward stage 3 (Hartley combine)
// tab[4096..6144) twI  [r][n] (c, s)        inverse stages 1,2
// tab[6144..8192) twIw [r][n] (c+s, s-c)    inverse stage 3
__global__ __launch_bounds__(256) void k_tables(float2* __restrict__ tab) {
    const int t = threadIdx.x;
    for (int i = t; i < 2048; i += 256) {
        const int a = i >> 5, f = i & 31;           // a = spatial idx (64), f = freq idx (32)
        const int k = (f < 16) ? f : f + 32;
        const float ang = (float)((k * a) & 63) * 0.09817477042468103f; // 2*pi/64
        float s, c;
        sincosf(ang, &s, &c);
        tab[i] = make_float2(c, s);
        tab[2048 + i] = make_float2(c + s, s - c);
        tab[4096 + (f << 6) + a] = make_float2(c, s);
        tab[6144 + (f << 6) + a] = make_float2(c + s, s - c);
    }
}

// ---------------- forward stage 1: partial DFT along W. x:(B,D,H,W,C) -> (B,D,H,F2,C)
__global__ __launch_bounds__(256) void k_fwd_w(const float* __restrict__ x,
                                               const float2* __restrict__ twF,
                                               float* __restrict__ re1, float* __restrict__ im1) {
    __shared__ __attribute__((aligned(16))) float xs[64][64];
    __shared__ __attribute__((aligned(16))) float2 tw[64][32]; // [w][f]
    const int blk = blockIdx.x;           // (b*64+d)*64+h
    const int t = threadIdx.x;
    const float* xp = x + (size_t)blk * 4096;
    for (int i = t; i < 1024; i += 256)
        *(float4*)&xs[i >> 4][(i & 15) * 4] = *(const float4*)&xp[i * 4];
    for (int i = t; i < 2048; i += 256) ((float2*)tw)[i] = twF[i];
    __syncthreads();
    const int c0 = (t & 15) * 4;
    const int f = t >> 4;                 // 0..15 (handles f and f+16)
    float ar0[4] = {}, ai0[4] = {}, ar1[4] = {}, ai1[4] = {};
    #pragma unroll 8
    for (int w = 0; w < 64; ++w) {
        const float4 xv = *(const float4*)&xs[w][c0];
        const float2 t0 = tw[w][f];
        const float2 t1 = tw[w][f + 16];
        const float xa[4] = {xv.x, xv.y, xv.z, xv.w};
        #pragma unroll
        for (int c = 0; c < 4; ++c) {
            ar0[c] = fmaf(xa[c], t0.x, ar0[c]);
            ai0[c] = fmaf(xa[c], -t0.y, ai0[c]);
            ar1[c] = fmaf(xa[c], t1.x, ar1[c]);
            ai1[c] = fmaf(xa[c], -t1.y, ai1[c]);
        }
    }
    const size_t base = (size_t)blk * 2048;
    float4 o;
    o.x=ar0[0]; o.y=ar0[1]; o.z=ar0[2]; o.w=ar0[3]; *(float4*)&re1[base + f*64 + c0] = o;
    o.x=ai0[0]; o.y=ai0[1]; o.z=ai0[2]; o.w=ai0[3]; *(float4*)&im1[base + f*64 + c0] = o;
    o.x=ar1[0]; o.y=ar1[1]; o.z=ar1[2]; o.w=ar1[3]; *(float4*)&re1[base + (f+16)*64 + c0] = o;
    o.x=ai1[0]; o.y=ai1[1]; o.z=ai1[2]; o.w=ai1[3]; *(float4*)&im1[base + (f+16)*64 + c0] = o;
}

// ---------------- forward stage 2: partial DFT along H (complex). -> (B,D,F1,F2,C)
__global__ __launch_bounds__(256) void k_fwd_h(const float* __restrict__ re1, const float* __restrict__ im1,
                                               const float2* __restrict__ twF,
                                               float* __restrict__ re2, float* __restrict__ im2) {
    __shared__ __attribute__((aligned(16))) float rs[64][64], is[64][64];
    __shared__ __attribute__((aligned(16))) float2 tw[64][32]; // [h][f]
    const int blk = blockIdx.x;           // bd*32 + f2
    const int f2 = blk & 31, bd = blk >> 5;
    const int t = threadIdx.x;
    for (int i = t; i < 1024; i += 256) {
        const int h = i >> 4, c4 = (i & 15) * 4;
        const size_t src = ((size_t)(bd * 64 + h) * 32 + f2) * 64 + c4;
        *(float4*)&rs[h][c4] = *(const float4*)&re1[src];
        *(float4*)&is[h][c4] = *(const float4*)&im1[src];
    }
    for (int i = t; i < 2048; i += 256) ((float2*)tw)[i] = twF[i];
    __syncthreads();
    const int c0 = (t & 15) * 4;
    const int f = t >> 4;
    float ar0[4] = {}, ai0[4] = {}, ar1[4] = {}, ai1[4] = {};
    #pragma unroll 4
    for (int h = 0; h < 64; ++h) {
        const float4 rv4 = *(const float4*)&rs[h][c0];
        const float4 iv4 = *(const float4*)&is[h][c0];
        const float2 t0 = tw[h][f];
        const float2 t1 = tw[h][f + 16];
        const float ra[4] = {rv4.x, rv4.y, rv4.z, rv4.w};
        const float ia[4] = {iv4.x, iv4.y, iv4.z, iv4.w};
        #pragma unroll
        for (int c = 0; c < 4; ++c) {
            ar0[c] = fmaf(ra[c], t0.x, ar0[c]); ar0[c] = fmaf(ia[c], t0.y, ar0[c]);
            ai0[c] = fmaf(ia[c], t0.x, ai0[c]); ai0[c] = fmaf(ra[c], -t0.y, ai0[c]);
            ar1[c] = fmaf(ra[c], t1.x, ar1[c]); ar1[c] = fmaf(ia[c], t1.y, ar1[c]);
            ai1[c] = fmaf(ia[c], t1.x, ai1[c]); ai1[c] = fmaf(ra[c], -t1.y, ai1[c]);
        }
    }
    float4 o;
    size_t dst = ((size_t)(bd * 32 + f) * 32 + f2) * 64 + c0;
    o.x=ar0[0]; o.y=ar0[1]; o.z=ar0[2]; o.w=ar0[3]; *(float4*)&re2[dst] = o;
    o.x=ai0[0]; o.y=ai0[1]; o.z=ai0[2]; o.w=ai0[3]; *(float4*)&im2[dst] = o;
    dst = ((size_t)(bd * 32 + f + 16) * 32 + f2) * 64 + c0;
    o.x=ar1[0]; o.y=ar1[1]; o.z=ar1[2]; o.w=ar1[3]; *(float4*)&re2[dst] = o;
    o.x=ai1[0]; o.y=ai1[1]; o.z=ai1[2]; o.w=ai1[3]; *(float4*)&im2[dst] = o;
}

// ---------------- forward stage 3: partial DFT along D + Hartley combine -> xt (B,F0,F1,F2,C)
__global__ __launch_bounds__(256) void k_fwd_d(const float* __restrict__ re2, const float* __restrict__ im2,
                                               const float2* __restrict__ twFd,
                                               float* __restrict__ xt) {
    __shared__ __attribute__((aligned(16))) float rs[64][64], is[64][64];
    __shared__ __attribute__((aligned(16))) float2 tw[64][32]; // [d][f] pairs (c+s, s-c)
    const int blk = blockIdx.x;           // b*1024 + f1*32 + f2
    const int f2 = blk & 31, f1 = (blk >> 5) & 31, b = blk >> 10;
    const int t = threadIdx.x;
    for (int i = t; i < 1024; i += 256) {
        const int d = i >> 4, c4 = (i & 15) * 4;
        const size_t src = (((size_t)(b * 64 + d) * 32 + f1) * 32 + f2) * 64 + c4;
        *(float4*)&rs[d][c4] = *(const float4*)&re2[src];
        *(float4*)&is[d][c4] = *(const float4*)&im2[src];
    }
    for (int i = t; i < 2048; i += 256) ((float2*)tw)[i] = twFd[i];
    __syncthreads();
    const int c0 = (t & 15) * 4;
    const int f = t >> 4;
    float a0[4] = {}, a1[4] = {};
    #pragma unroll 4
    for (int d = 0; d < 64; ++d) {
        const float4 rv4 = *(const float4*)&rs[d][c0];
        const float4 iv4 = *(const float4*)&is[d][c0];
        const float2 p0 = tw[d][f];
        const float2 p1 = tw[d][f + 16];
        const float ra[4] = {rv4.x, rv4.y, rv4.z, rv4.w};
        const float ia[4] = {iv4.x, iv4.y, iv4.z, iv4.w};
        #pragma unroll
        for (int c = 0; c < 4; ++c) {
            a0[c] = fmaf(ra[c], p0.x, a0[c]); a0[c] = fmaf(ia[c], p0.y, a0[c]);
            a1[c] = fmaf(ra[c], p1.x, a1[c]); a1[c] = fmaf(ia[c], p1.y, a1[c]);
        }
    }
    float4 o;
    size_t dst = (((size_t)(b * 32 + f) * 32 + f1) * 32 + f2) * 64 + c0;
    o.x=a0[0]; o.y=a0[1]; o.z=a0[2]; o.w=a0[3]; *(float4*)&xt[dst] = o;
    dst = (((size_t)(b * 32 + f + 16) * 32 + f1) * 32 + f2) * 64 + c0;
    o.x=a1[0]; o.y=a1[1]; o.z=a1[2]; o.w=a1[3]; *(float4*)&xt[dst] = o;
}

// ---------------- QKV projection + grouping -> f16 (B*H, L=512, R=1024)
__global__ __launch_bounds__(128) void k_qkv(const float* __restrict__ xt,
                                             const float* __restrict__ Wq, const float* __restrict__ Wk,
                                             const float* __restrict__ Wv,
                                             _Float16* __restrict__ Qh, _Float16* __restrict__ Kh,
                                             _Float16* __restrict__ Vh) {
    __shared__ float xs[64][65];
    const int blk = blockIdx.x;           // b*512 + l
    const int l = blk & 511, b = blk >> 9;
    const int nw = l & 7, nh = (l >> 3) & 7, nd = l >> 6;
    const int t = threadIdx.x;            // 128: key = t>>3, n = t&7
    for (int i = t; i < 4096; i += 128) {
        const int pofs = i >> 6, c = i & 63;
        const int f0 = nd * 4 + (pofs >> 4);
        const int f1 = nh * 4 + ((pofs >> 2) & 3);
        const int f2 = nw * 4 + (pofs & 3);
        xs[pofs][c] = xt[((((size_t)b * 32 + f0) * 32 + f1) * 32 + f2) * 64 + c];
    }
    __syncthreads();
    const int kn = t;
    const int key = kn >> 3, n = kn & 7;
    #pragma unroll 1
    for (int p0 = 0; p0 < 64; p0 += 16) {
        float accq[16], acck[16], accv[16];
        #pragma unroll
        for (int i = 0; i < 16; ++i) { accq[i] = 0.f; acck[i] = 0.f; accv[i] = 0.f; }
        #pragma unroll 1
        for (int c0 = 0; c0 < 64; c0 += 16) {
            float wq[16], wk[16], wv[16];
            #pragma unroll
            for (int c = 0; c < 16; ++c) {
                wq[c] = Wq[(c0 + c) * 128 + kn];
                wk[c] = Wk[(c0 + c) * 128 + kn];
                wv[c] = Wv[(c0 + c) * 128 + kn];
            }
            #pragma unroll
            for (int p = 0; p < 16; ++p) {
                #pragma unroll
                for (int c = 0; c < 16; ++c) {
                    const float xv = xs[p0 + p][c0 + c];
                    accq[p] = fmaf(xv, wq[c], accq[p]);
                    acck[p] = fmaf(xv, wk[c], acck[p]);
                    accv[p] = fmaf(xv, wv[c], accv[p]);
                }
            }
        }
        const size_t base = (((size_t)(b * 8 + n) * 512 + l) * 1024 + key * 64 + p0);
        #pragma unroll
        for (int p = 0; p < 16; ++p) {
            Qh[base + p] = (_Float16)accq[p];
            Kh[base + p] = (_Float16)acck[p];
            Vh[base + p] = (_Float16)accv[p];
        }
    }
}

// ---------------- V transpose per bh: (512 l, 1024 r) -> Vt (1024 r, 512 l)
__global__ __launch_bounds__(256) void k_vt(const _Float16* __restrict__ Vh, _Float16* __restrict__ Vt) {
    __shared__ __attribute__((aligned(16))) _Float16 ldsT[64][72];
    const int blk = blockIdx.x;           // bh*128 + rt*8 + lt
    const int lt = blk & 7, rt = (blk >> 3) & 15, bh = blk >> 7;
    const int l0 = lt * 64, r0 = rt * 64;
    const int t = threadIdx.x;
    const int o8 = t & 7, li = t >> 3;    // li 0..31
    const _Float16* src = Vh + (size_t)bh * 512 * 1024;
    _Float16* dst = Vt + (size_t)bh * 1024 * 512;
    #pragma unroll
    for (int p = 0; p < 2; ++p) {
        const int lr = li + p * 32;
        half8 v = *(const half8*)&src[(size_t)(l0 + lr) * 1024 + r0 + o8 * 8];
        #pragma unroll
        for (int jj = 0; jj < 8; ++jj) ldsT[o8 * 8 + jj][lr] = v[jj];
    }
    __syncthreads();
    #pragma unroll
    for (int p = 0; p < 2; ++p) {
        const int rr = li + p * 32;
        half8 v = *(const half8*)&ldsT[rr][o8 * 8];
        *(half8*)&dst[(size_t)(r0 + rr) * 512 + l0 + o8 * 8] = v;
    }
}

// ---------------- MFMA f16 GEMM: C[512 x NTOT] = A[512 x KTOT] * B[NTOT x KTOT]^T per bh
// A row-major (m,k), B row-major (n,k). 128x128 tile, 4 waves (2x2), BK=64, XOR-swizzled LDS.
template<int KTOT, int NTOT, bool DOSELU, typename CT>
__global__ __launch_bounds__(256) void k_gemm(const _Float16* __restrict__ Ag,
                                              const _Float16* __restrict__ Bg,
                                              CT* __restrict__ Cg, float oscale) {
    __shared__ __attribute__((aligned(16))) _Float16 As[128 * 64];
    __shared__ __attribute__((aligned(16))) _Float16 Bs[128 * 64];
    const int bh = blockIdx.z;
    const int m0 = blockIdx.y * 128, n0 = blockIdx.x * 128;
    const _Float16* Ab = Ag + (size_t)bh * 512 * KTOT;
    const _Float16* Bb = Bg + (size_t)bh * NTOT * KTOT;
    CT* Cb = Cg + (size_t)bh * 512 * NTOT;
    const int t = threadIdx.x;
    const int o8 = t & 7, rstg = t >> 3;  // staging: octet, row-base (0..31)
    const int wv = t >> 6, l = t & 63, lr = l & 15, lk = l >> 4;
    const int wm = (wv >> 1) * 64, wn = (wv & 1) * 64;
    f32x4 acc[4][4];
    #pragma unroll
    for (int i = 0; i < 4; ++i)
        #pragma unroll
        for (int j = 0; j < 4; ++j) acc[i][j] = (f32x4){0.f, 0.f, 0.f, 0.f};
    #pragma unroll 1
    for (int k0 = 0; k0 < KTOT; k0 += 64) {
        if (k0) __syncthreads();
        #pragma unroll
        for (int p = 0; p < 4; ++p) {
            const int row = rstg + 32 * p;
            half8 va = *(const half8*)&Ab[(size_t)(m0 + row) * KTOT + k0 + o8 * 8];
            half8 vb = *(const half8*)&Bb[(size_t)(n0 + row) * KTOT + k0 + o8 * 8];
            const int by = (row * 128 + o8 * 16) ^ ((row & 7) << 4);
            *(half8*)((char*)As + by) = va;
            *(half8*)((char*)Bs + by) = vb;
        }
        __syncthreads();
        #pragma unroll
        for (int ks = 0; ks < 2; ++ks) {
            half8 af[4], bf[4];
            #pragma unroll
            for (int i = 0; i < 4; ++i) {
                const int ra = wm + i * 16 + lr;
                af[i] = *(const half8*)((const char*)As +
                        ((ra * 128 + ks * 64 + lk * 16) ^ ((ra & 7) << 4)));
                const int rb = wn + i * 16 + lr;
                bf[i] = *(const half8*)((const char*)Bs +
                        ((rb * 128 + ks * 64 + lk * 16) ^ ((rb & 7) << 4)));
            }
            #pragma unroll
            for (int i = 0; i < 4; ++i)
                #pragma unroll
                for (int j = 0; j < 4; ++j)
                    acc[i][j] = __builtin_amdgcn_mfma_f32_16x16x32_f16(af[i], bf[j], acc[i][j], 0, 0, 0);
        }
    }
    #pragma unroll
    for (int i = 0; i < 4; ++i) {
        #pragma unroll
        for (int r = 0; r < 4; ++r) {
            const int grow = m0 + wm + i * 16 + lk * 4 + r;
            #pragma unroll
            for (int j = 0; j < 4; ++j) {
                float v = acc[i][j][r];
                if (DOSELU) v = selu_f(v);
                v *= oscale;
                Cb[(size_t)grow * NTOT + n0 + wn + j * 16 + lr] = (CT)v;
            }
        }
    }
}

// ---------------- output projection + ungrouping
__global__ __launch_bounds__(256) void k_oproj(const float* __restrict__ Ob,
                                               const float* __restrict__ Wo,
                                               float* __restrict__ op) {
    __shared__ float Os[8][1024];
    __shared__ float Ws[2048];
    const int blk = blockIdx.x;           // b*512 + l
    const int l = blk & 511, b = blk >> 9;
    const int t = threadIdx.x;
    for (int i = t; i < 8192; i += 256) {
        const int h = i >> 10, r = i & 1023;
        Os[h][r] = Ob[((size_t)(b * 8 + h) * 512 + l) * 1024 + r];
    }
    for (int i = t; i < 2048; i += 256) Ws[i] = Wo[i];
    __syncthreads();
    const int pofs = t >> 2, o0 = (t & 3) * 4;
    float acc[4] = {0.f, 0.f, 0.f, 0.f};
    #pragma unroll
    for (int h = 0; h < 8; ++h) {
        #pragma unroll
        for (int val = 0; val < 16; ++val) {
            const float ov = Os[h][val * 64 + pofs];
            const int wi = (val * 8 + h) * 16;
            #pragma unroll
            for (int j = 0; j < 4; ++j) acc[j] = fmaf(ov, Ws[wi + o0 + j], acc[j]);
        }
    }
    const int nw = l & 7, nh = (l >> 3) & 7, nd = l >> 6;
    const int f0 = nd * 4 + (pofs >> 4);
    const int f1 = nh * 4 + ((pofs >> 2) & 3);
    const int f2 = nw * 4 + (pofs & 3);
    const size_t base = ((((size_t)b * 32 + f0) * 32 + f1) * 32 + f2) * 16 + o0;
    op[base + 0] = acc[0]; op[base + 1] = acc[1]; op[base + 2] = acc[2]; op[base + 3] = acc[3];
}

// ---------------- inverse stage 1: corner freqs (32) -> D (64), real in, complex out
__global__ __launch_bounds__(256) void k_inv_d(const float* __restrict__ op,
                                               const float2* __restrict__ twI,
                                               float* __restrict__ ire, float* __restrict__ iim) {
    __shared__ __attribute__((aligned(16))) float s4[32][16];
    __shared__ __attribute__((aligned(16))) float2 tw[32][64]; // [r][d]
    const int blk = blockIdx.x;           // b*1024 + k1*32 + k2
    const int k2 = blk & 31, k1 = (blk >> 5) & 31, b = blk >> 10;
    const int t = threadIdx.x;
    for (int i = t; i < 512; i += 256)
        s4[i >> 4][i & 15] = op[((size_t)(b * 32 + (i >> 4)) * 1024 + k1 * 32 + k2) * 16 + (i & 15)];
    for (int i = t; i < 2048; i += 256) ((float2*)tw)[i] = twI[i];
    __syncthreads();
    const int oq = (t & 3) * 4, d = t >> 2;
    float ar[4] = {}, ai[4] = {};
    #pragma unroll 8
    for (int r = 0; r < 32; ++r) {
        const float4 v4 = *(const float4*)&s4[r][oq];
        const float2 w = tw[r][d];
        const float va[4] = {v4.x, v4.y, v4.z, v4.w};
        #pragma unroll
        for (int c = 0; c < 4; ++c) {
            ar[c] = fmaf(va[c], w.x, ar[c]);
            ai[c] = fmaf(va[c], -w.y, ai[c]);
        }
    }
    const size_t dst = ((size_t)(b * 64 + d) * 1024 + k1 * 32 + k2) * 16 + oq;
    float4 o;
    o.x=ar[0]; o.y=ar[1]; o.z=ar[2]; o.w=ar[3]; *(float4*)&ire[dst] = o;
    o.x=ai[0]; o.y=ai[1]; o.z=ai[2]; o.w=ai[3]; *(float4*)&iim[dst] = o;
}

// ---------------- inverse stage 2: along k1 -> H (complex)
__global__ __launch_bounds__(256) void k_inv_h(const float* __restrict__ ire, const float* __restrict__ iim,
                                               const float2* __restrict__ twI,
                                               float* __restrict__ ore, float* __restrict__ oim) {
    __shared__ __attribute__((aligned(16))) float sr[32][16], si[32][16];
    __shared__ __attribute__((aligned(16))) float2 tw[32][64]; // [r][h]
    const int blk = blockIdx.x;           // b*2048 + d*32 + k2
    const int k2 = blk & 31, d = (blk >> 5) & 63, b = blk >> 11;
    const int t = threadIdx.x;
    for (int i = t; i < 512; i += 256) {
        const size_t src = ((size_t)(b * 64 + d) * 1024 + (i >> 4) * 32 + k2) * 16 + (i & 15);
        sr[i >> 4][i & 15] = ire[src];
        si[i >> 4][i & 15] = iim[src];
    }
    for (int i = t; i < 2048; i += 256) ((float2*)tw)[i] = twI[i];
    __syncthreads();
    const int oq = (t & 3) * 4, h = t >> 2;
    float ar[4] = {}, ai[4] = {};
    #pragma unroll 8
    for (int r = 0; r < 32; ++r) {
        const float4 rv4 = *(const float4*)&sr[r][oq];
        const float4 iv4 = *(const float4*)&si[r][oq];
        const float2 w = tw[r][h];
        const float ra[4] = {rv4.x, rv4.y, rv4.z, rv4.w};
        const float ia[4] = {iv4.x, iv4.y, iv4.z, iv4.w};
        #pragma unroll
        for (int c = 0; c < 4; ++c) {
            ar[c] = fmaf(ra[c], w.x, ar[c]); ar[c] = fmaf(ia[c], w.y, ar[c]);
            ai[c] = fmaf(ia[c], w.x, ai[c]); ai[c] = fmaf(ra[c], -w.y, ai[c]);
        }
    }
    const size_t dst = (((size_t)(b * 64 + d) * 64 + h) * 32 + k2) * 16 + oq;
    float4 o;
    o.x=ar[0]; o.y=ar[1]; o.z=ar[2]; o.w=ar[3]; *(float4*)&ore[dst] = o;
    o.x=ai[0]; o.y=ai[1]; o.z=ai[2]; o.w=ai[3]; *(float4*)&oim[dst] = o;
}

// ---------------- inverse stage 3: along k2 -> W, Hartley combine, /64^3
__global__ __launch_bounds__(256) void k_inv_w(const float* __restrict__ ire, const float* __restrict__ iim,
                                               const float2* __restrict__ twIw,
                                               float* __restrict__ outp) {
    __shared__ __attribute__((aligned(16))) float sr[32][16], si[32][16];
    __shared__ __attribute__((aligned(16))) float2 tw[32][64]; // [r][w] pairs (c+s, s-c)
    const int blk = blockIdx.x;           // b*4096 + d*64 + h
    const int t = threadIdx.x;
    for (int i = t; i < 512; i += 256) {
        const size_t src = (size_t)blk * 512 + i;
        sr[i >> 4][i & 15] = ire[src];
        si[i >> 4][i & 15] = iim[src];
    }
    for (int i = t; i < 2048; i += 256) ((float2*)tw)[i] = twIw[i];
    __syncthreads();
    const int oq = (t & 3) * 4, w = t >> 2;
    float a[4] = {};
    #pragma unroll 8
    for (int r = 0; r < 32; ++r) {
        const float4 rv4 = *(const float4*)&sr[r][oq];
        const float4 iv4 = *(const float4*)&si[r][oq];
        const float2 p = tw[r][w];
        const float ra[4] = {rv4.x, rv4.y, rv4.z, rv4.w};
        const float ia[4] = {iv4.x, iv4.y, iv4.z, iv4.w};
        #pragma unroll
        for (int c = 0; c < 4; ++c) {
            a[c] = fmaf(ra[c], p.x, a[c]);
            a[c] = fmaf(ia[c], p.y, a[c]);
        }
    }
    const float sc = 3.814697265625e-06f; // 1/64^3
    float4 o;
    o.x=a[0]*sc; o.y=a[1]*sc; o.z=a[2]*sc; o.w=a[3]*sc;
    *(float4*)&outp[((size_t)blk * 64 + w) * 16 + oq] = o;
}

extern "C" void kernel_launch(void* const* d_in, const int* in_sizes, int n_in,
                              void* d_out, int out_size, void* d_ws, size_t ws_size,
                              hipStream_t stream) {
    const float* x  = (const float*)d_in[0];
    const float* Wq = (const float*)d_in[1];
    const float* Wk = (const float*)d_in[2];
    const float* Wv = (const float*)d_in[3];
    const float* Wo = (const float*)d_in[4];
    float* outp = (float*)d_out;
    float* ws = (float*)d_ws;

    // twiddle tables
    float2* tabs = (float2*)ws;                 // 8192 float2 = 16384 floats
    const float2* twF  = tabs;
    const float2* twFd = tabs + 2048;
    const float2* twI  = tabs + 4096;
    const float2* twIw = tabs + 6144;

    // workspace layout (float offsets); peak ~201.5 MB
    float* re1 = ws + 32768;                    // 16777216
    float* im1 = ws + 16809984;                 // 16777216
    float* re2 = ws + 33587200;                 // 8388608
    float* im2 = ws + 41975808;                 // 8388608 -> end 50364416
    float* xt  = ws + 32768;                    // 4194304 (reuses re1)
    _Float16* Qh = (_Float16*)(ws + 4227072);   // 8.4M f16 (in old re1)
    _Float16* Kh = (_Float16*)(ws + 8421376);
    _Float16* Vh = (_Float16*)(ws + 12615680);
    _Float16* Vt = (_Float16*)(ws + 16809984);  // old im1
    _Float16* P  = (_Float16*)(ws + 21004288);  // 4.2M f16
    float* Ob  = ws + 23101440;                 // 8388608
    float* op  = ws + 31490048;                 // 1048576
    float* ire1 = ws + 32538624;                // 2097152
    float* iim1 = ws + 34635776;                // 2097152
    float* ire2 = ws + 36732928;                // 4194304
    float* iim2 = ws + 40927232;                // 4194304 -> end 45121536

    k_tables<<<1, 256, 0, stream>>>(tabs);
    k_fwd_w<<<8192, 256, 0, stream>>>(x, twF, re1, im1);
    k_fwd_h<<<4096, 256, 0, stream>>>(re1, im1, twF, re2, im2);
    k_fwd_d<<<2048, 256, 0, stream>>>(re2, im2, twFd, xt);
    k_qkv<<<1024, 128, 0, stream>>>(xt, Wq, Wk, Wv, Qh, Kh, Vh);
    k_vt<<<2048, 256, 0, stream>>>(Vh, Vt);
    k_gemm<1024, 512, true, _Float16><<<dim3(4, 4, 16), 256, 0, stream>>>(Qh, Kh, P, 0.00390625f);
    k_gemm<512, 1024, false, float><<<dim3(8, 4, 16), 256, 0, stream>>>(P, Vt, Ob, 256.0f);
    k_oproj<<<1024, 256, 0, stream>>>(Ob, Wo, op);
    k_inv_d<<<2048, 256, 0, stream>>>(op, twI, ire1, iim1);
    k_inv_h<<<4096, 256, 0, stream>>>(ire1, iim1, twI, ire2, iim2);
    k_inv_w<<<8192, 256, 0, stream>>>(ire2, iim2, twIw, outp);
}

// Round 3
// 442.229 us; speedup vs baseline: 2.8367x; 1.2103x over previous
//
#include <hip/hip_runtime.h>
#include <math.h>

// B=2, spatial 64^3, C=64, F=32 kept freqs/axis, heads=8, key=val=16,
// patch 4^3 -> tokens L=512, grouped channels R=1024.
// Forward DHT + QKV are MFMA f16 batched GEMMs against constant twiddle
// matrices; intermediates f16. Attention GEMMs MFMA f16. Inverse DHT fp32 VALU.

typedef _Float16 half8 __attribute__((ext_vector_type(8)));
typedef float f32x4 __attribute__((ext_vector_type(4)));

static __device__ __forceinline__ float selu_f(float v) {
    return 1.0507009873554805f * (v > 0.f ? v : 1.6732632423543772f * (expf(v) - 1.f));
}

// ---------------- constant tables (once per launch)
// A1g[64][64]:   row 2f+ri, col w:   ri0: cos, ri1: -sin           (stage 1)
// A2p[64][128]:  row 2f+ro, col ri*64+h: ro0:{c,s} ro1:{-s,c}      (stage 2, ri-major k)
// A3p[32][128]:  row f,     col ri*64+d: {c+s, s-c}                (stage 3 + Hartley)
// WqT/WkT/WvT[128][64]: transposed projection weights (f16)
// twI/twIw: float2 tables for the fp32 inverse stages
__global__ __launch_bounds__(256) void k_tables(const float* __restrict__ Wq, const float* __restrict__ Wk,
                                                const float* __restrict__ Wv,
                                                _Float16* __restrict__ A1g, _Float16* __restrict__ A2p,
                                                _Float16* __restrict__ A3p,
                                                _Float16* __restrict__ WqT, _Float16* __restrict__ WkT,
                                                _Float16* __restrict__ WvT,
                                                float2* __restrict__ twI, float2* __restrict__ twIw) {
    const int t = threadIdx.x;
    for (int i = t; i < 2048; i += 256) {
        const int f = i & 31, a = i >> 5;             // a = spatial idx [0,64)
        const int k = (f < 16) ? f : f + 32;
        const float ang = (float)((k * a) & 63) * 0.09817477042468103f; // 2*pi/64
        float s, c;
        sincosf(ang, &s, &c);
        A1g[(2 * f + 0) * 64 + a] = (_Float16)c;
        A1g[(2 * f + 1) * 64 + a] = (_Float16)(-s);
        A2p[(2 * f + 0) * 128 + a]      = (_Float16)c;
        A2p[(2 * f + 0) * 128 + 64 + a] = (_Float16)s;
        A2p[(2 * f + 1) * 128 + a]      = (_Float16)(-s);
        A2p[(2 * f + 1) * 128 + 64 + a] = (_Float16)c;
        A3p[f * 128 + a]      = (_Float16)(c + s);
        A3p[f * 128 + 64 + a] = (_Float16)(s - c);
        twI[(f << 6) + a]  = make_float2(c, s);
        twIw[(f << 6) + a] = make_float2(c + s, s - c);
    }
    for (int i = t; i < 8192; i += 256) {
        const int kn = i >> 6, c = i & 63;
        WqT[i] = (_Float16)Wq[c * 128 + kn];
        WkT[i] = (_Float16)Wk[c * 128 + kn];
        WvT[i] = (_Float16)Wv[c * 128 + kn];
    }
}

// ---------------- fwd stage 1: x:(B,D,H,W,C) f32 -> t1[bdh][2f2+ri][c] f16
// per block: out(64x64) = A1(64x64) * X(w,c); M=2f2+ri, K=w, N=c
__global__ __launch_bounds__(256) void k_fwd_w(const float* __restrict__ x,
                                               const _Float16* __restrict__ A1g,
                                               _Float16* __restrict__ t1) {
    __shared__ _Float16 X1[64][72];       // [c][w], rowlen 72 (144B, 16B aligned)
    const int blk = blockIdx.x;           // (b*64+d)*64+h
    const int t = threadIdx.x;
    const float* xp = x + (size_t)blk * 4096;
    for (int i = t; i < 1024; i += 256) {
        const float4 v = ((const float4*)xp)[i];
        const int w = i >> 4, c0 = (i & 15) * 4;
        X1[c0 + 0][w] = (_Float16)v.x;
        X1[c0 + 1][w] = (_Float16)v.y;
        X1[c0 + 2][w] = (_Float16)v.z;
        X1[c0 + 3][w] = (_Float16)v.w;
    }
    __syncthreads();
    const int wv = t >> 6, l = t & 63, lr = l & 15, lk = l >> 4;
    const int mh = (wv >> 1) * 32, nh = (wv & 1) * 32;
    half8 af[2][2], bf[2][2];
    #pragma unroll
    for (int i = 0; i < 2; ++i)
        #pragma unroll
        for (int ks = 0; ks < 2; ++ks) {
            af[i][ks] = *(const half8*)&A1g[(mh + i * 16 + lr) * 64 + ks * 32 + lk * 8];
            bf[i][ks] = *(const half8*)&X1[nh + i * 16 + lr][ks * 32 + lk * 8];
        }
    f32x4 acc[2][2];
    #pragma unroll
    for (int i = 0; i < 2; ++i)
        #pragma unroll
        for (int j = 0; j < 2; ++j) acc[i][j] = (f32x4){0.f, 0.f, 0.f, 0.f};
    #pragma unroll
    for (int ks = 0; ks < 2; ++ks)
        #pragma unroll
        for (int i = 0; i < 2; ++i)
            #pragma unroll
            for (int j = 0; j < 2; ++j)
                acc[i][j] = __builtin_amdgcn_mfma_f32_16x16x32_f16(af[i][ks], bf[j][ks], acc[i][j], 0, 0, 0);
    _Float16* op = t1 + (size_t)blk * 4096;
    #pragma unroll
    for (int i = 0; i < 2; ++i)
        #pragma unroll
        for (int j = 0; j < 2; ++j)
            #pragma unroll
            for (int r = 0; r < 4; ++r)
                op[(mh + i * 16 + lk * 4 + r) * 64 + nh + j * 16 + lr] = (_Float16)acc[i][j][r];
}

// ---------------- fwd stage 2: t1 -> t2[(bd*32+f2)][2f1+ro][c] f16
// per (bd,f2): out(64x64) = A2p(64x128) * X2; K = ri*64+h
__global__ __launch_bounds__(256) void k_fh(const _Float16* __restrict__ t1,
                                            const _Float16* __restrict__ A2p,
                                            _Float16* __restrict__ t2) {
    __shared__ _Float16 X2[2][64][72];    // [ri][c][h]
    const int blk = blockIdx.x;           // bd*32 + f2
    const int f2 = blk & 31, bd = blk >> 5;
    const int t = threadIdx.x;
    for (int i = t; i < 1024; i += 256) {
        const int h = i >> 4, q = i & 15;
        const half8 v = *(const half8*)(t1 + ((size_t)(bd * 64 + h) << 12) + (f2 << 7) + (q << 3));
        const int ri = q >> 3, c0 = (q & 7) * 8;
        #pragma unroll
        for (int j = 0; j < 8; ++j) X2[ri][c0 + j][h] = v[j];
    }
    __syncthreads();
    const int wv = t >> 6, l = t & 63, lr = l & 15, lk = l >> 4;
    const int mh = (wv >> 1) * 32, nh = (wv & 1) * 32;
    half8 af[2][4], bf[2][4];
    #pragma unroll
    for (int i = 0; i < 2; ++i)
        #pragma unroll
        for (int ks = 0; ks < 4; ++ks) {
            af[i][ks] = *(const half8*)&A2p[(mh + i * 16 + lr) * 128 + ks * 32 + lk * 8];
            bf[i][ks] = *(const half8*)&X2[ks >> 1][nh + i * 16 + lr][(ks & 1) * 32 + lk * 8];
        }
    f32x4 acc[2][2];
    #pragma unroll
    for (int i = 0; i < 2; ++i)
        #pragma unroll
        for (int j = 0; j < 2; ++j) acc[i][j] = (f32x4){0.f, 0.f, 0.f, 0.f};
    #pragma unroll
    for (int ks = 0; ks < 4; ++ks)
        #pragma unroll
        for (int i = 0; i < 2; ++i)
            #pragma unroll
            for (int j = 0; j < 2; ++j)
                acc[i][j] = __builtin_amdgcn_mfma_f32_16x16x32_f16(af[i][ks], bf[j][ks], acc[i][j], 0, 0, 0);
    _Float16* op = t2 + ((size_t)(bd * 32 + f2) << 12);
    #pragma unroll
    for (int i = 0; i < 2; ++i)
        #pragma unroll
        for (int j = 0; j < 2; ++j)
            #pragma unroll
            for (int r = 0; r < 4; ++r)
                op[(mh + i * 16 + lk * 4 + r) * 64 + nh + j * 16 + lr] = (_Float16)acc[i][j][r];
}

// ---------------- fwd stage 3: t2 -> xt[((b*32+f1)*32+f2)][f0][c] f16 (Hartley)
__global__ __launch_bounds__(256) void k_fd(const _Float16* __restrict__ t2,
                                            const _Float16* __restrict__ A3p,
                                            _Float16* __restrict__ xt) {
    __shared__ _Float16 X3[2][64][72];    // [ri][c][d]
    const int blk = blockIdx.x;           // b*1024 + f1*32 + f2
    const int f2 = blk & 31, f1 = (blk >> 5) & 31, b = blk >> 10;
    const int t = threadIdx.x;
    for (int i = t; i < 1024; i += 256) {
        const int d = i >> 4, q = i & 15;
        const half8 v = *(const half8*)(t2 + (((size_t)(b * 64 + d) * 32 + f2) << 12) + (f1 << 7) + (q << 3));
        const int ri = q >> 3, c0 = (q & 7) * 8;
        #pragma unroll
        for (int j = 0; j < 8; ++j) X3[ri][c0 + j][d] = v[j];
    }
    __syncthreads();
    const int wv = t >> 6, l = t & 63, lr = l & 15, lk = l >> 4;
    const int it = wv >> 1, nh = (wv & 1) * 32;   // i-tile (M=32 -> 2 tiles), n-half
    half8 af[4], bf[2][4];
    #pragma unroll
    for (int ks = 0; ks < 4; ++ks) {
        af[ks] = *(const half8*)&A3p[(it * 16 + lr) * 128 + ks * 32 + lk * 8];
        #pragma unroll
        for (int j = 0; j < 2; ++j)
            bf[j][ks] = *(const half8*)&X3[ks >> 1][nh + j * 16 + lr][(ks & 1) * 32 + lk * 8];
    }
    f32x4 acc[2];
    acc[0] = (f32x4){0.f, 0.f, 0.f, 0.f};
    acc[1] = (f32x4){0.f, 0.f, 0.f, 0.f};
    #pragma unroll
    for (int ks = 0; ks < 4; ++ks)
        #pragma unroll
        for (int j = 0; j < 2; ++j)
            acc[j] = __builtin_amdgcn_mfma_f32_16x16x32_f16(af[ks], bf[j][ks], acc[j], 0, 0, 0);
    _Float16* op = xt + ((size_t)blk << 11);
    #pragma unroll
    for (int j = 0; j < 2; ++j)
        #pragma unroll
        for (int r = 0; r < 4; ++r)
            op[(it * 16 + lk * 4 + r) * 64 + nh + j * 16 + lr] = (_Float16)acc[j][r];
}

// ---------------- QKV projection + grouping -> f16 (B*H, L=512, R=1024), r = p*16+key
__global__ __launch_bounds__(256) void k_qkv(const _Float16* __restrict__ xt,
                                             const _Float16* __restrict__ WqT, const _Float16* __restrict__ WkT,
                                             const _Float16* __restrict__ WvT,
                                             _Float16* __restrict__ Qh, _Float16* __restrict__ Kh,
                                             _Float16* __restrict__ Vh) {
    __shared__ _Float16 xs[64][72];       // [p][c]
    __shared__ _Float16 ldso[8][1024];    // [n][r] repack for coalesced writes
    const int blk = blockIdx.x;           // b*512 + l
    const int lI = blk & 511, b = blk >> 9;
    const int tw_ = lI & 7, th_ = (lI >> 3) & 7, td_ = lI >> 6;
    const int t = threadIdx.x;
    for (int i = t; i < 512; i += 256) {
        const int pofs = i >> 3, c0 = (i & 7) * 8;
        const int f0 = td_ * 4 + (pofs >> 4);
        const int f1 = th_ * 4 + ((pofs >> 2) & 3);
        const int f2 = tw_ * 4 + (pofs & 3);
        const half8 v = *(const half8*)(xt + ((((size_t)(b * 32 + f1) * 32 + f2) * 32 + f0) << 6) + c0);
        *(half8*)&xs[pofs][c0] = v;
    }
    __syncthreads();
    const int wv = t >> 6, l = t & 63, lr = l & 15, lk = l >> 4;
    const int knb = wv * 32;              // kn-slice per wave
    half8 af[4][2];
    #pragma unroll
    for (int i = 0; i < 4; ++i)
        #pragma unroll
        for (int ks = 0; ks < 2; ++ks)
            af[i][ks] = *(const half8*)&xs[i * 16 + lr][ks * 32 + lk * 8];

    auto do_mat = [&](const _Float16* __restrict__ WT, _Float16* __restrict__ dst) {
        half8 bf[2][2];
        #pragma unroll
        for (int j = 0; j < 2; ++j)
            #pragma unroll
            for (int ks = 0; ks < 2; ++ks)
                bf[j][ks] = *(const half8*)&WT[(knb + j * 16 + lr) * 64 + ks * 32 + lk * 8];
        f32x4 acc[4][2];
        #pragma unroll
        for (int i = 0; i < 4; ++i)
            #pragma unroll
            for (int j = 0; j < 2; ++j) acc[i][j] = (f32x4){0.f, 0.f, 0.f, 0.f};
        #pragma unroll
        for (int ks = 0; ks < 2; ++ks)
            #pragma unroll
            for (int i = 0; i < 4; ++i)
                #pragma unroll
                for (int j = 0; j < 2; ++j)
                    acc[i][j] = __builtin_amdgcn_mfma_f32_16x16x32_f16(af[i][ks], bf[j][ks], acc[i][j], 0, 0, 0);
        #pragma unroll
        for (int i = 0; i < 4; ++i)
            #pragma unroll
            for (int j = 0; j < 2; ++j)
                #pragma unroll
                for (int r = 0; r < 4; ++r) {
                    const int p = i * 16 + lk * 4 + r;
                    const int kn = knb + j * 16 + lr;
                    ldso[kn & 7][p * 16 + (kn >> 3)] = (_Float16)acc[i][j][r];
                }
        __syncthreads();
        for (int i = t; i < 1024; i += 256) {
            const int n = i >> 7, o8 = (i & 127) * 8;
            *(half8*)(dst + (((size_t)(b * 8 + n) * 512 + lI) << 10) + o8) = *(const half8*)&ldso[n][o8];
        }
        __syncthreads();
    };
    do_mat(WqT, Qh);
    do_mat(WkT, Kh);
    do_mat(WvT, Vh);
}

// ---------------- V transpose per bh: (512 l, 1024 r) -> Vt (1024 r, 512 l)
__global__ __launch_bounds__(256) void k_vt(const _Float16* __restrict__ Vh, _Float16* __restrict__ Vt) {
    __shared__ __attribute__((aligned(16))) _Float16 ldsT[64][72];
    const int blk = blockIdx.x;           // bh*128 + rt*8 + lt
    const int lt = blk & 7, rt = (blk >> 3) & 15, bh = blk >> 7;
    const int l0 = lt * 64, r0 = rt * 64;
    const int t = threadIdx.x;
    const int o8 = t & 7, li = t >> 3;    // li 0..31
    const _Float16* src = Vh + (size_t)bh * 512 * 1024;
    _Float16* dst = Vt + (size_t)bh * 1024 * 512;
    #pragma unroll
    for (int p = 0; p < 2; ++p) {
        const int lr = li + p * 32;
        half8 v = *(const half8*)&src[(size_t)(l0 + lr) * 1024 + r0 + o8 * 8];
        #pragma unroll
        for (int jj = 0; jj < 8; ++jj) ldsT[o8 * 8 + jj][lr] = v[jj];
    }
    __syncthreads();
    #pragma unroll
    for (int p = 0; p < 2; ++p) {
        const int rr = li + p * 32;
        half8 v = *(const half8*)&ldsT[rr][o8 * 8];
        *(half8*)&dst[(size_t)(r0 + rr) * 512 + l0 + o8 * 8] = v;
    }
}

// ---------------- MFMA f16 GEMM: C[512 x NTOT] = A[512 x KTOT] * B[NTOT x KTOT]^T per bh
template<int KTOT, int NTOT, bool DOSELU, typename CT>
__global__ __launch_bounds__(256) void k_gemm(const _Float16* __restrict__ Ag,
                                              const _Float16* __restrict__ Bg,
                                              CT* __restrict__ Cg, float oscale) {
    __shared__ __attribute__((aligned(16))) _Float16 As[128 * 64];
    __shared__ __attribute__((aligned(16))) _Float16 Bs[128 * 64];
    const int bh = blockIdx.z;
    const int m0 = blockIdx.y * 128, n0 = blockIdx.x * 128;
    const _Float16* Ab = Ag + (size_t)bh * 512 * KTOT;
    const _Float16* Bb = Bg + (size_t)bh * NTOT * KTOT;
    CT* Cb = Cg + (size_t)bh * 512 * NTOT;
    const int t = threadIdx.x;
    const int o8 = t & 7, rstg = t >> 3;
    const int wv = t >> 6, l = t & 63, lr = l & 15, lk = l >> 4;
    const int wm = (wv >> 1) * 64, wn = (wv & 1) * 64;
    f32x4 acc[4][4];
    #pragma unroll
    for (int i = 0; i < 4; ++i)
        #pragma unroll
        for (int j = 0; j < 4; ++j) acc[i][j] = (f32x4){0.f, 0.f, 0.f, 0.f};
    #pragma unroll 1
    for (int k0 = 0; k0 < KTOT; k0 += 64) {
        if (k0) __syncthreads();
        #pragma unroll
        for (int p = 0; p < 4; ++p) {
            const int row = rstg + 32 * p;
            half8 va = *(const half8*)&Ab[(size_t)(m0 + row) * KTOT + k0 + o8 * 8];
            half8 vb = *(const half8*)&Bb[(size_t)(n0 + row) * KTOT + k0 + o8 * 8];
            const int by = (row * 128 + o8 * 16) ^ ((row & 7) << 4);
            *(half8*)((char*)As + by) = va;
            *(half8*)((char*)Bs + by) = vb;
        }
        __syncthreads();
        #pragma unroll
        for (int ks = 0; ks < 2; ++ks) {
            half8 af[4], bf[4];
            #pragma unroll
            for (int i = 0; i < 4; ++i) {
                const int ra = wm + i * 16 + lr;
                af[i] = *(const half8*)((const char*)As +
                        ((ra * 128 + ks * 64 + lk * 16) ^ ((ra & 7) << 4)));
                const int rb = wn + i * 16 + lr;
                bf[i] = *(const half8*)((const char*)Bs +
                        ((rb * 128 + ks * 64 + lk * 16) ^ ((rb & 7) << 4)));
            }
            #pragma unroll
            for (int i = 0; i < 4; ++i)
                #pragma unroll
                for (int j = 0; j < 4; ++j)
                    acc[i][j] = __builtin_amdgcn_mfma_f32_16x16x32_f16(af[i], bf[j], acc[i][j], 0, 0, 0);
        }
    }
    #pragma unroll
    for (int i = 0; i < 4; ++i) {
        #pragma unroll
        for (int r = 0; r < 4; ++r) {
            const int grow = m0 + wm + i * 16 + lk * 4 + r;
            #pragma unroll
            for (int j = 0; j < 4; ++j) {
                float v = acc[i][j][r];
                if (DOSELU) v = selu_f(v);
                v *= oscale;
                Cb[(size_t)grow * NTOT + n0 + wn + j * 16 + lr] = (CT)v;
            }
        }
    }
}

// ---------------- output projection + ungrouping (r = pofs*16 + val)
__global__ __launch_bounds__(256) void k_oproj(const float* __restrict__ Ob,
                                               const float* __restrict__ Wo,
                                               float* __restrict__ op) {
    __shared__ float Os[8][1024];
    __shared__ float Ws[2048];
    const int blk = blockIdx.x;           // b*512 + l
    const int lI = blk & 511, b = blk >> 9;
    const int t = threadIdx.x;
    for (int i = t; i < 8192; i += 256) {
        const int h = i >> 10, r = i & 1023;
        Os[h][r] = Ob[((size_t)(b * 8 + h) * 512 + lI) * 1024 + r];
    }
    for (int i = t; i < 2048; i += 256) Ws[i] = Wo[i];
    __syncthreads();
    const int pofs = t >> 2, o0 = (t & 3) * 4;
    float acc[4] = {0.f, 0.f, 0.f, 0.f};
    #pragma unroll
    for (int h = 0; h < 8; ++h) {
        #pragma unroll
        for (int val = 0; val < 16; ++val) {
            const float ov = Os[h][pofs * 16 + val];
            const int wi = (val * 8 + h) * 16;
            #pragma unroll
            for (int j = 0; j < 4; ++j) acc[j] = fmaf(ov, Ws[wi + o0 + j], acc[j]);
        }
    }
    const int nw = lI & 7, nh = (lI >> 3) & 7, nd = lI >> 6;
    const int f0 = nd * 4 + (pofs >> 4);
    const int f1 = nh * 4 + ((pofs >> 2) & 3);
    const int f2 = nw * 4 + (pofs & 3);
    const size_t base = ((((size_t)b * 32 + f0) * 32 + f1) * 32 + f2) * 16 + o0;
    op[base + 0] = acc[0]; op[base + 1] = acc[1]; op[base + 2] = acc[2]; op[base + 3] = acc[3];
}

// ---------------- inverse stage 1: corner freqs (32) -> D (64), real in, complex out
__global__ __launch_bounds__(256) void k_inv_d(const float* __restrict__ op,
                                               const float2* __restrict__ twI,
                                               float* __restrict__ ire, float* __restrict__ iim) {
    __shared__ __attribute__((aligned(16))) float s4[32][16];
    __shared__ __attribute__((aligned(16))) float2 tw[32][64]; // [r][d]
    const int blk = blockIdx.x;           // b*1024 + k1*32 + k2
    const int k2 = blk & 31, k1 = (blk >> 5) & 31, b = blk >> 10;
    const int t = threadIdx.x;
    for (int i = t; i < 512; i += 256)
        s4[i >> 4][i & 15] = op[((size_t)(b * 32 + (i >> 4)) * 1024 + k1 * 32 + k2) * 16 + (i & 15)];
    for (int i = t; i < 2048; i += 256) ((float2*)tw)[i] = twI[i];
    __syncthreads();
    const int oq = (t & 3) * 4, d = t >> 2;
    float ar[4] = {}, ai[4] = {};
    #pragma unroll 8
    for (int r = 0; r < 32; ++r) {
        const float4 v4 = *(const float4*)&s4[r][oq];
        const float2 w = tw[r][d];
        const float va[4] = {v4.x, v4.y, v4.z, v4.w};
        #pragma unroll
        for (int c = 0; c < 4; ++c) {
            ar[c] = fmaf(va[c], w.x, ar[c]);
            ai[c] = fmaf(va[c], -w.y, ai[c]);
        }
    }
    const size_t dst = ((size_t)(b * 64 + d) * 1024 + k1 * 32 + k2) * 16 + oq;
    float4 o;
    o.x=ar[0]; o.y=ar[1]; o.z=ar[2]; o.w=ar[3]; *(float4*)&ire[dst] = o;
    o.x=ai[0]; o.y=ai[1]; o.z=ai[2]; o.w=ai[3]; *(float4*)&iim[dst] = o;
}

// ---------------- inverse stage 2: along k1 -> H (complex)
__global__ __launch_bounds__(256) void k_inv_h(const float* __restrict__ ire, const float* __restrict__ iim,
                                               const float2* __restrict__ twI,
                                               float* __restrict__ ore, float* __restrict__ oim) {
    __shared__ __attribute__((aligned(16))) float sr[32][16], si[32][16];
    __shared__ __attribute__((aligned(16))) float2 tw[32][64]; // [r][h]
    const int blk = blockIdx.x;           // b*2048 + d*32 + k2
    const int k2 = blk & 31, d = (blk >> 5) & 63, b = blk >> 11;
    const int t = threadIdx.x;
    for (int i = t; i < 512; i += 256) {
        const size_t src = ((size_t)(b * 64 + d) * 1024 + (i >> 4) * 32 + k2) * 16 + (i & 15);
        sr[i >> 4][i & 15] = ire[src];
        si[i >> 4][i & 15] = iim[src];
    }
    for (int i = t; i < 2048; i += 256) ((float2*)tw)[i] = twI[i];
    __syncthreads();
    const int oq = (t & 3) * 4, h = t >> 2;
    float ar[4] = {}, ai[4] = {};
    #pragma unroll 8
    for (int r = 0; r < 32; ++r) {
        const float4 rv4 = *(const float4*)&sr[r][oq];
        const float4 iv4 = *(const float4*)&si[r][oq];
        const float2 w = tw[r][h];
        const float ra[4] = {rv4.x, rv4.y, rv4.z, rv4.w};
        const float ia[4] = {iv4.x, iv4.y, iv4.z, iv4.w};
        #pragma unroll
        for (int c = 0; c < 4; ++c) {
            ar[c] = fmaf(ra[c], w.x, ar[c]); ar[c] = fmaf(ia[c], w.y, ar[c]);
            ai[c] = fmaf(ia[c], w.x, ai[c]); ai[c] = fmaf(ra[c], -w.y, ai[c]);
        }
    }
    const size_t dst = (((size_t)(b * 64 + d) * 64 + h) * 32 + k2) * 16 + oq;
    float4 o;
    o.x=ar[0]; o.y=ar[1]; o.z=ar[2]; o.w=ar[3]; *(float4*)&ore[dst] = o;
    o.x=ai[0]; o.y=ai[1]; o.z=ai[2]; o.w=ai[3]; *(float4*)&oim[dst] = o;
}

// ---------------- inverse stage 3: along k2 -> W, Hartley combine, /64^3
__global__ __launch_bounds__(256) void k_inv_w(const float* __restrict__ ire, const float* __restrict__ iim,
                                               const float2* __restrict__ twIw,
                                               float* __restrict__ outp) {
    __shared__ __attribute__((aligned(16))) float sr[32][16], si[32][16];
    __shared__ __attribute__((aligned(16))) float2 tw[32][64]; // [r][w] pairs (c+s, s-c)
    const int blk = blockIdx.x;           // b*4096 + d*64 + h
    const int t = threadIdx.x;
    for (int i = t; i < 512; i += 256) {
        const size_t src = (size_t)blk * 512 + i;
        sr[i >> 4][i & 15] = ire[src];
        si[i >> 4][i & 15] = iim[src];
    }
    for (int i = t; i < 2048; i += 256) ((float2*)tw)[i] = twIw[i];
    __syncthreads();
    const int oq = (t & 3) * 4, w = t >> 2;
    float a[4] = {};
    #pragma unroll 8
    for (int r = 0; r < 32; ++r) {
        const float4 rv4 = *(const float4*)&sr[r][oq];
        const float4 iv4 = *(const float4*)&si[r][oq];
        const float2 p = tw[r][w];
        const float ra[4] = {rv4.x, rv4.y, rv4.z, rv4.w};
        const float ia[4] = {iv4.x, iv4.y, iv4.z, iv4.w};
        #pragma unroll
        for (int c = 0; c < 4; ++c) {
            a[c] = fmaf(ra[c], p.x, a[c]);
            a[c] = fmaf(ia[c], p.y, a[c]);
        }
    }
    const float sc = 3.814697265625e-06f; // 1/64^3
    float4 o;
    o.x=a[0]*sc; o.y=a[1]*sc; o.z=a[2]*sc; o.w=a[3]*sc;
    *(float4*)&outp[((size_t)blk * 64 + w) * 16 + oq] = o;
}

extern "C" void kernel_launch(void* const* d_in, const int* in_sizes, int n_in,
                              void* d_out, int out_size, void* d_ws, size_t ws_size,
                              hipStream_t stream) {
    const float* x  = (const float*)d_in[0];
    const float* Wq = (const float*)d_in[1];
    const float* Wk = (const float*)d_in[2];
    const float* Wv = (const float*)d_in[3];
    const float* Wo = (const float*)d_in[4];
    float* outp = (float*)d_out;
    float* ws = (float*)d_ws;

    // constant tables (float offsets)
    _Float16* A1g = (_Float16*)(ws + 0);        // 4096 f16
    _Float16* A2p = (_Float16*)(ws + 2048);     // 8192 f16
    _Float16* A3p = (_Float16*)(ws + 6144);     // 4096 f16
    _Float16* WqT = (_Float16*)(ws + 8192);     // 8192 f16
    _Float16* WkT = (_Float16*)(ws + 12288);
    _Float16* WvT = (_Float16*)(ws + 16384);
    float2* twI   = (float2*)(ws + 20480);      // 2048 float2
    float2* twIw  = (float2*)(ws + 24576);

    // tensors (float offsets); peak ~176 MB with reuse
    _Float16* t1 = (_Float16*)(ws + 32768);     // 33.5M f16
    _Float16* t2 = (_Float16*)(ws + 16809984);  // 16.8M f16
    _Float16* xt = (_Float16*)(ws + 25198592);  // 4.2M f16
    _Float16* Qh = (_Float16*)(ws + 27295744);  // 8.4M f16
    _Float16* Kh = (_Float16*)(ws + 31490048);
    _Float16* Vh = (_Float16*)(ws + 35684352);
    _Float16* Vt = (_Float16*)(ws + 39878656);
    _Float16* P  = (_Float16*)(ws + 32768);     // reuses t1 (dead after k_fh)
    float* Ob    = ws + 16809984;               // reuses t2+xt region (dead)
    float* op    = ws + 27295744;               // reuses Qh (dead after gemm1)
    float* ire1  = ws + 31490048;               // reuses Kh
    float* iim1  = ws + 33587200;
    float* ire2  = ws + 35684352;               // reuses Vh/Vt
    float* iim2  = ws + 39878656;

    k_tables<<<1, 256, 0, stream>>>(Wq, Wk, Wv, A1g, A2p, A3p, WqT, WkT, WvT, twI, twIw);
    k_fwd_w<<<8192, 256, 0, stream>>>(x, A1g, t1);
    k_fh<<<4096, 256, 0, stream>>>(t1, A2p, t2);
    k_fd<<<2048, 256, 0, stream>>>(t2, A3p, xt);
    k_qkv<<<1024, 256, 0, stream>>>(xt, WqT, WkT, WvT, Qh, Kh, Vh);
    k_vt<<<2048, 256, 0, stream>>>(Vh, Vt);
    k_gemm<1024, 512, true, _Float16><<<dim3(4, 4, 16), 256, 0, stream>>>(Qh, Kh, P, 0.00390625f);
    k_gemm<512, 1024, false, float><<<dim3(8, 4, 16), 256, 0, stream>>>(P, Vt, Ob, 256.0f);
    k_oproj<<<1024, 256, 0, stream>>>(Ob, Wo, op);
    k_inv_d<<<2048, 256, 0, stream>>>(op, twI, ire1, iim1);
    k_inv_h<<<4096, 256, 0, stream>>>(ire1, iim1, twI, ire2, iim2);
    k_inv_w<<<8192, 256, 0, stream>>>(ire2, iim2, twIw, outp);
}